// Round 18
// baseline (7143.195 us; speedup 1.0000x reference)
//
#include <hip/hip_runtime.h>

typedef unsigned short ushortT;
typedef __attribute__((ext_vector_type(8))) short short8;
typedef __attribute__((ext_vector_type(8))) unsigned short ushort8;
typedef __attribute__((ext_vector_type(4))) unsigned short ushort4v;
typedef __attribute__((ext_vector_type(4))) float f32x4;

#define DEVINL __device__ __forceinline__

DEVINL ushortT f2bf(float f) {
    unsigned u = __builtin_bit_cast(unsigned, f);
    u += 0x7FFFu + ((u >> 16) & 1u);   // round-to-nearest-even
    return (ushortT)(u >> 16);
}
DEVINL float bf2f(ushortT h) {
    unsigned u = ((unsigned)h) << 16;
    return __builtin_bit_cast(float, u);
}
DEVINL float gelu_tanh(float x) {
    float x3 = x * x * x;
    return 0.5f * x * (1.0f + tanhf(0.7978845608028654f * (x + 0.044715f * x3)));
}

#define GLOAD_LDS16(g, l)                                                     \
    __builtin_amdgcn_global_load_lds(                                         \
        (const __attribute__((address_space(1))) void*)(g),                   \
        (__attribute__((address_space(3))) void*)(l), 16, 0, 0)

#define WAITV(n) asm volatile("s_waitcnt vmcnt(" #n ")" ::: "memory")
#define MEMFENCE() asm volatile("" ::: "memory")
#define BAR() __builtin_amdgcn_s_barrier()
#define BARF() MEMFENCE(); BAR(); MEMFENCE()

// ---------------------------------------------------------------------------
__global__ __launch_bounds__(256) void cast_bf16_4(const float* __restrict__ in,
                                                   ushortT* __restrict__ out, long n4) {
    long i = (long)blockIdx.x * 256 + threadIdx.x;
    if (i < n4) {
        const float* p = in + i * 4;
        ushort4v o;
        o[0] = f2bf(p[0]); o[1] = f2bf(p[1]); o[2] = f2bf(p[2]); o[3] = f2bf(p[3]);
        ((ushort4v*)out)[i] = o;
    }
}

// ---------------------------------------------------------------------------
__global__ __launch_bounds__(256) void transpose_cast(const float* __restrict__ in,
                                                      ushortT* __restrict__ out,
                                                      int K, int N, int Npad) {
    __shared__ float tile[32][33];
    long zi = (long)blockIdx.z * K * N;
    long zo = (long)blockIdx.z * Npad * K;
    const float* ip = in + zi;
    ushortT* op = out + zo;
    int t = threadIdx.x, bx = blockIdx.x, by = blockIdx.y;
#pragma unroll
    for (int i = 0; i < 4; i++) {
        int idx = i * 256 + t, r = idx >> 5, c = idx & 31;
        int col = bx * 32 + c;
        tile[r][c] = (col < N) ? ip[(long)(by * 32 + r) * N + col] : 0.0f;
    }
    __syncthreads();
#pragma unroll
    for (int i = 0; i < 4; i++) {
        int idx = i * 256 + t, r = idx >> 5, c = idx & 31;
        op[(long)(bx * 32 + r) * K + by * 32 + c] = f2bf(tile[c][r]);
    }
}

// pad a per-layer bias vector from n_in to n_out with zeros. total = L*n_out.
__global__ __launch_bounds__(256) void pad_bias(const float* __restrict__ in,
                                                float* __restrict__ out,
                                                int n_in, int n_out, int total) {
    int i = blockIdx.x * 256 + threadIdx.x;
    if (i < total) {
        int l = i / n_out, c = i % n_out;
        out[i] = (c < n_in) ? in[l * n_in + c] : 0.0f;
    }
}

// ---------------------------------------------------------------------------
// LayerNorm over HID=1280, bf16 in -> bf16 out. One block (256 thr) per row.
__global__ __launch_bounds__(256) void ln_bf16(const ushortT* __restrict__ in,
                                               const float* __restrict__ w,
                                               const float* __restrict__ b,
                                               ushortT* __restrict__ out) {
    const int row = blockIdx.x;
    const ushortT* x = in + (long)row * 1280;
    __shared__ float red[4];
    const int t = threadIdx.x;
    float v[8];
    float s = 0.f;
    if (t < 160) {
        ushort8 u = *(const ushort8*)(x + t * 8);
#pragma unroll
        for (int i = 0; i < 8; i++) { v[i] = bf2f(u[i]); s += v[i]; }
    } else {
#pragma unroll
        for (int i = 0; i < 8; i++) v[i] = 0.f;
    }
#pragma unroll
    for (int o = 32; o > 0; o >>= 1) s += __shfl_xor(s, o);
    int wave = t >> 6;
    if ((t & 63) == 0) red[wave] = s;
    __syncthreads();
    float mean = (red[0] + red[1] + red[2] + red[3]) * (1.0f / 1280.0f);
    float q = 0.f;
    if (t < 160) {
#pragma unroll
        for (int i = 0; i < 8; i++) { float d = v[i] - mean; q += d * d; }
    }
#pragma unroll
    for (int o = 32; o > 0; o >>= 1) q += __shfl_xor(q, o);
    __syncthreads();
    if ((t & 63) == 0) red[wave] = q;
    __syncthreads();
    float var = (red[0] + red[1] + red[2] + red[3]) * (1.0f / 1280.0f);
    float rs = rsqrtf(var + 1e-6f);
    if (t < 160) {
        ushort8 o8;
#pragma unroll
        for (int i = 0; i < 8; i++) {
            int c = t * 8 + i;
            o8[i] = f2bf((v[i] - mean) * rs * w[c] + b[c]);
        }
        *(ushort8*)(out + (long)row * 1280 + t * 8) = o8;
    }
}

// ---------------------------------------------------------------------------
// Kernel A (r15-verified): 128x128, 4 waves, BK=32, double-buffered 32KB LDS,
// __launch_bounds__(256,2). Used for: pe, proj, fc2, merger-fc2
// (N=1280-class: grid 1280 = 5 blocks/CU, no tail; measured 347 us on fc2).
#define GSTAGE(mat, ls, base, ld, k0, buf)                                    \
    _Pragma("unroll") for (int j = 0; j < 2; j++) {                           \
        int c = j * 256 + t; int sr = c >> 2, sl = c & 3;                     \
        GLOAD_LDS16(mat + (base + sr) * (size_t)ld + (k0) + ((sl ^ ((sr >> 1) & 3)) * 8), \
                    &ls[buf][c * 8]);                                         \
    }
#define GREAD(buf)                                                            \
    _Pragma("unroll") for (int m = 0; m < 4; m++) {                           \
        int r = wr * 64 + m * 16 + lr;                                        \
        aF[m] = *(const short8*)&lsA[buf][r * 32 + ((lg ^ ((r >> 1) & 3)) * 8)]; \
    }                                                                         \
    _Pragma("unroll") for (int n = 0; n < 4; n++) {                           \
        int r = wc * 64 + n * 16 + lr;                                        \
        bF[n] = *(const short8*)&lsB[buf][r * 32 + ((lg ^ ((r >> 1) & 3)) * 8)]; \
    }
#define GMFMA()                                                               \
    __builtin_amdgcn_s_setprio(1);                                            \
    _Pragma("unroll") for (int m = 0; m < 4; m++)                             \
    _Pragma("unroll") for (int n = 0; n < 4; n++)                             \
        acc[m][n] = __builtin_amdgcn_mfma_f32_16x16x32_bf16(                  \
            aF[m], bF[n], acc[m][n], 0, 0, 0);                                \
    __builtin_amdgcn_s_setprio(0);

template <bool OBF, bool RESB, bool GEL>
__global__ __launch_bounds__(256, 2)
void gemm_db(const ushortT* __restrict__ A, const ushortT* __restrict__ Bt,
             const float* __restrict__ bias, const ushortT* __restrict__ resb,
             void* __restrict__ out, int M, int N, int K, int lda, int ldb) {
    __shared__ ushortT lsA[2][4096];
    __shared__ ushortT lsB[2][4096];
    const int t = threadIdx.x;
    const int lane = t & 63, lr = lane & 15, lg = lane >> 4;
    const int wave = t >> 6;
    const int wr = wave >> 1, wc = wave & 1;

    const int nwg = gridDim.x, orig = blockIdx.x;
    const int q = nwg >> 3, r8 = nwg & 7;
    const int xcd = orig & 7, loc = orig >> 3;
    const int wg = (xcd < r8 ? xcd * (q + 1) : r8 * (q + 1) + (xcd - r8) * q) + loc;
    const int gx = N >> 7;
    const size_t brow = (size_t)(wg / gx) * 128;
    const size_t bcol = (size_t)(wg % gx) * 128;

    f32x4 acc[4][4];
#pragma unroll
    for (int m = 0; m < 4; m++)
#pragma unroll
        for (int n = 0; n < 4; n++) acc[m][n] = f32x4{0.f, 0.f, 0.f, 0.f};

    GSTAGE(A, lsA, brow, lda, 0, 0);
    GSTAGE(Bt, lsB, bcol, ldb, 0, 0);
    WAITV(0); BARF();

    short8 aF[4], bF[4];
    const int NT = K >> 5;
    int cur = 0;
    for (int tt = 0; tt < NT; ++tt) {
        MEMFENCE();
        GREAD(cur);
        if (tt + 1 < NT) {
            const int k1 = (tt + 1) << 5;
            GSTAGE(A, lsA, brow, lda, k1, cur ^ 1);
            GSTAGE(Bt, lsB, bcol, ldb, k1, cur ^ 1);
        }
        GMFMA();
        if (tt + 1 < NT) {
            WAITV(0);
            BARF();
        }
        cur ^= 1;
    }

#pragma unroll
    for (int m = 0; m < 4; m++) {
#pragma unroll
        for (int n = 0; n < 4; n++) {
#pragma unroll
            for (int rr = 0; rr < 4; rr++) {
                size_t row = brow + wr * 64 + m * 16 + lg * 4 + rr;
                size_t col = bcol + wc * 64 + n * 16 + lr;
                float v = acc[m][n][rr] + bias[col];
                if (RESB) v += bf2f(resb[row * N + col]);
                if (GEL) v = gelu_tanh(v);
                if (OBF) ((ushortT*)out)[row * N + col] = f2bf(v);
                else     ((float*)out)[row * N + col] = v;
            }
        }
    }
}

// ---------------------------------------------------------------------------
// Kernel B (r2-verified): 256x256 tile, BK=64, 8 waves (2x4), 512 threads,
// 128KB double-buffered LDS, classic 2-phase prefetch (__syncthreads drains).
// In r2 these dispatches ran faster than the 128^2 kernel's 356us on the
// same shapes. Used for: qkv, fc1, merger-fc1 (K=1280-class, wide N).
template <int BM, int BN, int WN, bool OBF, bool GEL>
__global__ __launch_bounds__(128 * WN, 2)
void gemm2ph(const ushortT* __restrict__ A, const ushortT* __restrict__ Bt,
             const float* __restrict__ bias,
             void* __restrict__ out, int M, int N, int K, int lda, int ldb) {
    constexpr int THREADS = 128 * WN;
    constexpr int MR = BM / 32;            // frags per wave in M (WM=2)
    constexpr int NR = BN / (WN * 16);     // frags per wave in N
    constexpr int AOPS = (BM * 8) / THREADS;   // 16B chunks per thread per A stage
    constexpr int BOPS = (BN * 8) / THREADS;
    __shared__ ushortT lsA[2][BM * 64];
    __shared__ ushortT lsB[2][BN * 64];

    const int t = threadIdx.x;
    const int lane = t & 63, lr = lane & 15, lg = lane >> 4;
    const int wave = t >> 6;
    const int wr = wave / WN, wc = wave % WN;

    // bijective XCD swizzle (m204)
    const int nwg = gridDim.x;
    const int orig = blockIdx.x;
    const int q = nwg >> 3, r8 = nwg & 7;
    const int xcd = orig & 7, loc = orig >> 3;
    const int wg = (xcd < r8 ? xcd * (q + 1) : r8 * (q + 1) + (xcd - r8) * q) + loc;
    const int gx = N / BN;
    const int bx = wg % gx, by = wg / gx;
    const long brow = (long)by * BM;
    const long bcol = (long)bx * BN;

    auto stage = [&](int buf, int k0) {
#pragma unroll
        for (int j = 0; j < AOPS; j++) {
            int idx = j * THREADS + t;
            int row = idx >> 3, slot = idx & 7;
            int ss = slot ^ (row & 7);
            GLOAD_LDS16(A + (size_t)(brow + row) * lda + k0 + ss * 8,
                        &lsA[buf][idx * 8]);
        }
#pragma unroll
        for (int j = 0; j < BOPS; j++) {
            int idx = j * THREADS + t;
            int row = idx >> 3, slot = idx & 7;
            int ss = slot ^ (row & 7);
            GLOAD_LDS16(Bt + (size_t)(bcol + row) * ldb + k0 + ss * 8,
                        &lsB[buf][idx * 8]);
        }
    };

    f32x4 acc[MR][NR];
#pragma unroll
    for (int m = 0; m < MR; m++)
#pragma unroll
        for (int n = 0; n < NR; n++) acc[m][n] = f32x4{0.f, 0.f, 0.f, 0.f};

    stage(0, 0);
    __syncthreads();

    const int NT = K >> 6;
    for (int tt = 0; tt < NT; tt++) {
        const int cur = tt & 1;
        if (tt + 1 < NT) stage(cur ^ 1, (tt + 1) << 6);   // prefetch next tile
#pragma unroll
        for (int kk = 0; kk < 2; kk++) {
            short8 af[MR], bfg[NR];
#pragma unroll
            for (int m = 0; m < MR; m++) {
                int row = wr * (BM / 2) + m * 16 + lr;
                af[m] = *(const short8*)&lsA[cur][row * 64 + (((kk * 4 + lg) ^ (row & 7)) * 8)];
            }
#pragma unroll
            for (int n = 0; n < NR; n++) {
                int row = wc * (BN / WN) + n * 16 + lr;
                bfg[n] = *(const short8*)&lsB[cur][row * 64 + (((kk * 4 + lg) ^ (row & 7)) * 8)];
            }
#pragma unroll
            for (int m = 0; m < MR; m++)
#pragma unroll
                for (int n = 0; n < NR; n++)
                    acc[m][n] = __builtin_amdgcn_mfma_f32_16x16x32_bf16(af[m], bfg[n],
                                                                        acc[m][n], 0, 0, 0);
        }
        __syncthreads();   // drains vmcnt(0): next tile landed; buf[cur] reads done
    }

#pragma unroll
    for (int m = 0; m < MR; m++) {
#pragma unroll
        for (int n = 0; n < NR; n++) {
#pragma unroll
            for (int rr = 0; rr < 4; rr++) {
                size_t row = brow + wr * (BM / 2) + m * 16 + lg * 4 + rr;
                size_t col = bcol + wc * (BN / WN) + n * 16 + lr;
                float v = acc[m][n][rr] + bias[col];
                if (GEL) v = gelu_tanh(v);
                if (OBF) ((ushortT*)out)[row * N + col] = f2bf(v);
                else     ((float*)out)[row * N + col] = v;
            }
        }
    }
}

// ---------------------------------------------------------------------------
// windowed attention with fused RoPE: one block per (window of 64 tokens, head).
__global__ __launch_bounds__(256) void attn_win(const ushortT* __restrict__ qkv,
                                                const float* __restrict__ cosb,
                                                const float* __restrict__ sinb,
                                                ushortT* __restrict__ out) {
    const int w = blockIdx.x, h = blockIdx.y;
    __shared__ ushortT qs[64 * 96];
    __shared__ ushortT ks[64 * 96];
    __shared__ ushortT vt[80 * 80];
    __shared__ float   sc[64 * 65];
    __shared__ ushortT pb[64 * 80];
    const int t = threadIdx.x, wave = t >> 6, lane = t & 63, lr = lane & 15, lg = lane >> 4;
    const ushortT* bq = qkv + (long)w * 64 * 3840 + h * 80;

    for (int c = t; c < 640; c += 256) {
        int r = c / 10, cb = c % 10;
        const ushortT* qp = bq + (long)r * 3840;
        ushort8 qa = *(const ushort8*)(qp + cb * 8);
        ushort8 ka = *(const ushort8*)(qp + 1280 + cb * 8);
        int pcb = (cb < 5) ? cb + 5 : cb - 5;
        ushort8 qpr = *(const ushort8*)(qp + pcb * 8);
        ushort8 kpr = *(const ushort8*)(qp + 1280 + pcb * 8);
        long srow = (long)w * 64 + r;
        const float* cp = cosb + srow * 80 + cb * 8;
        const float* sp = sinb + srow * 80 + cb * 8;
        float sgn = (cb < 5) ? -1.f : 1.f;
        ushort8 qo, ko;
#pragma unroll
        for (int j = 0; j < 8; j++) {
            float c_ = cp[j], s_ = sp[j] * sgn;
            qo[j] = f2bf(bf2f(qa[j]) * c_ + bf2f(qpr[j]) * s_);
            ko[j] = f2bf(bf2f(ka[j]) * c_ + bf2f(kpr[j]) * s_);
        }
        *(ushort8*)&qs[r * 96 + cb * 8] = qo;
        *(ushort8*)&ks[r * 96 + cb * 8] = ko;
        ushort8 vv = *(const ushort8*)(qp + 2560 + cb * 8);
#pragma unroll
        for (int j = 0; j < 8; j++) vt[(cb * 8 + j) * 80 + r] = vv[j];
    }
    for (int idx = t; idx < 1024; idx += 256) {
        int r = idx >> 4, c2 = 80 + (idx & 15);
        qs[r * 96 + c2] = 0;
        ks[r * 96 + c2] = 0;
    }
    __syncthreads();

    f32x4 sa[4];
#pragma unroll
    for (int n = 0; n < 4; n++) sa[n] = f32x4{0.f, 0.f, 0.f, 0.f};
#pragma unroll
    for (int kk = 0; kk < 3; kk++) {
        short8 aq = *(const short8*)&qs[(wave * 16 + lr) * 96 + kk * 32 + lg * 8];
#pragma unroll
        for (int n = 0; n < 4; n++) {
            short8 bk = *(const short8*)&ks[(n * 16 + lr) * 96 + kk * 32 + lg * 8];
            sa[n] = __builtin_amdgcn_mfma_f32_16x16x32_bf16(aq, bk, sa[n], 0, 0, 0);
        }
    }
    const float scale = 0.11180339887498949f;
#pragma unroll
    for (int n = 0; n < 4; n++)
#pragma unroll
        for (int r = 0; r < 4; r++)
            sc[(wave * 16 + lg * 4 + r) * 65 + n * 16 + lr] = sa[n][r] * scale;
    __syncthreads();

    {
        int row = t >> 2, q4 = t & 3;
        float pv[16];
        float mx = -1e30f;
#pragma unroll
        for (int j = 0; j < 16; j++) { pv[j] = sc[row * 65 + q4 * 16 + j]; mx = fmaxf(mx, pv[j]); }
        mx = fmaxf(mx, __shfl_xor(mx, 1));
        mx = fmaxf(mx, __shfl_xor(mx, 2));
        float sum = 0.f;
#pragma unroll
        for (int j = 0; j < 16; j++) { pv[j] = __expf(pv[j] - mx); sum += pv[j]; }
        sum += __shfl_xor(sum, 1);
        sum += __shfl_xor(sum, 2);
        float inv = 1.0f / sum;
#pragma unroll
        for (int j = 0; j < 16; j++) pb[row * 80 + q4 * 16 + j] = f2bf(pv[j] * inv);
    }
    __syncthreads();

    f32x4 pa[5];
#pragma unroll
    for (int n = 0; n < 5; n++) pa[n] = f32x4{0.f, 0.f, 0.f, 0.f};
#pragma unroll
    for (int kk = 0; kk < 2; kk++) {
        short8 ap = *(const short8*)&pb[(wave * 16 + lr) * 80 + kk * 32 + lg * 8];
#pragma unroll
        for (int n = 0; n < 5; n++) {
            short8 bv = *(const short8*)&vt[(n * 16 + lr) * 80 + kk * 32 + lg * 8];
            pa[n] = __builtin_amdgcn_mfma_f32_16x16x32_bf16(ap, bv, pa[n], 0, 0, 0);
        }
    }
    ushortT* ob = out + (long)w * 64 * 1280 + h * 80;
#pragma unroll
    for (int n = 0; n < 5; n++)
#pragma unroll
        for (int r = 0; r < 4; r++)
            ob[(long)(wave * 16 + lg * 4 + r) * 1280 + n * 16 + lr] = f2bf(pa[n][r]);
}

// ---------------------------------------------------------------------------
extern "C" void kernel_launch(void* const* d_in, const int* in_sizes, int n_in,
                              void* d_out, int out_size, void* d_ws, size_t ws_size,
                              hipStream_t stream) {
    const float* x      = (const float*)d_in[0];
    const float* cosb   = (const float*)d_in[1];
    const float* sinb   = (const float*)d_in[2];
    const float* pe_w   = (const float*)d_in[4];
    const float* pe_b   = (const float*)d_in[5];
    const float* ln1_w  = (const float*)d_in[6];
    const float* ln1_b  = (const float*)d_in[7];
    const float* qkv_w  = (const float*)d_in[8];
    const float* qkv_b  = (const float*)d_in[9];
    const float* proj_w = (const float*)d_in[10];
    const float* proj_b = (const float*)d_in[11];
    const float* ln2_w  = (const float*)d_in[12];
    const float* ln2_b  = (const float*)d_in[13];
    const float* fc1_w  = (const float*)d_in[14];
    const float* fc1_b  = (const float*)d_in[15];
    const float* fc2_w  = (const float*)d_in[16];
    const float* fc2_b  = (const float*)d_in[17];
    const float* mln_w  = (const float*)d_in[18];
    const float* mln_b  = (const float*)d_in[19];
    const float* mfc1_w = (const float*)d_in[20];
    const float* mfc1_b = (const float*)d_in[21];
    const float* mfc2_w = (const float*)d_in[22];
    const float* mfc2_b = (const float*)d_in[23];

    char* ws = (char*)d_ws;
    size_t off = 0;
    auto alloc = [&](size_t bytes) -> char* {
        char* p = ws + off;
        off += (bytes + 255) & ~(size_t)255;
        return p;
    };
    ushortT* pe_wT   = (ushortT*)alloc((size_t)1280 * 1536 * 2);
    ushortT* qkv_wT  = (ushortT*)alloc((size_t)8 * 3840 * 1280 * 2);
    ushortT* proj_wT = (ushortT*)alloc((size_t)8 * 1280 * 1280 * 2);
    ushortT* fc1_wT  = (ushortT*)alloc((size_t)8 * 3584 * 1280 * 2);  // N padded 3456->3584
    ushortT* fc2_wT  = (ushortT*)alloc((size_t)8 * 1280 * 3456 * 2);
    ushortT* mfc1_wT = (ushortT*)alloc((size_t)5120 * 5120 * 2);
    ushortT* mfc2_wT = (ushortT*)alloc((size_t)2048 * 5120 * 2);
    float*   fc1_bp  = (float*)alloc((size_t)8 * 3584 * 4);
    ushortT* hbuf    = (ushortT*)alloc((size_t)16384 * 1280 * 2);     // residual, bf16
    ushortT* xn      = (ushortT*)alloc((size_t)16384 * 1280 * 2);
    ushortT* big     = (ushortT*)alloc((size_t)16384 * 3840 * 2);     // qkv / x_bf16 / ffn1
    ushortT* attnb   = (ushortT*)alloc((size_t)16384 * 1280 * 2);     // also merger t1

    ushortT* xbf  = big;
    ushortT* qkvb = big;
    ushortT* ffn1 = big;
    ushortT* t1   = attnb;

    transpose_cast<<<dim3(1280 / 32, 1536 / 32, 1), 256, 0, stream>>>(pe_w,   pe_wT,   1536, 1280, 1280);
    transpose_cast<<<dim3(3840 / 32, 1280 / 32, 8), 256, 0, stream>>>(qkv_w,  qkv_wT,  1280, 3840, 3840);
    transpose_cast<<<dim3(1280 / 32, 1280 / 32, 8), 256, 0, stream>>>(proj_w, proj_wT, 1280, 1280, 1280);
    transpose_cast<<<dim3(3584 / 32, 1280 / 32, 8), 256, 0, stream>>>(fc1_w,  fc1_wT,  1280, 3456, 3584);
    transpose_cast<<<dim3(1280 / 32, 3456 / 32, 8), 256, 0, stream>>>(fc2_w,  fc2_wT,  3456, 1280, 1280);
    transpose_cast<<<dim3(5120 / 32, 5120 / 32, 1), 256, 0, stream>>>(mfc1_w, mfc1_wT, 5120, 5120, 5120);
    transpose_cast<<<dim3(2048 / 32, 5120 / 32, 1), 256, 0, stream>>>(mfc2_w, mfc2_wT, 5120, 2048, 2048);
    pad_bias<<<(8 * 3584 + 255) / 256, 256, 0, stream>>>(fc1_b, fc1_bp, 3456, 3584, 8 * 3584);

    // --- patch embed: h = x @ pe_w + pe_b (h bf16) ---
    cast_bf16_4<<<(16384L * 1536 / 4 + 255) / 256, 256, 0, stream>>>(x, xbf, 16384L * 1536 / 4);
    gemm_db<true, false, false><<<dim3(128 * 10), 256, 0, stream>>>(
        xbf, pe_wT, pe_b, nullptr, hbuf, 16384, 1280, 1536, 1536, 1536);

    // --- transformer layers ---
    for (int l = 0; l < 8; l++) {
        ln_bf16<<<16384, 256, 0, stream>>>(hbuf, ln1_w + l * 1280, ln1_b + l * 1280, xn);
        gemm2ph<256, 256, 4, true, false><<<dim3(15 * 64), 512, 0, stream>>>(
            xn, qkv_wT + (size_t)l * 3840 * 1280, qkv_b + l * 3840, qkvb,
            16384, 3840, 1280, 1280, 1280);
        attn_win<<<dim3(256, 16), 256, 0, stream>>>(qkvb, cosb, sinb, attnb);
        gemm_db<true, true, false><<<dim3(128 * 10), 256, 0, stream>>>(
            attnb, proj_wT + (size_t)l * 1280 * 1280, proj_b + l * 1280, hbuf, hbuf,
            16384, 1280, 1280, 1280, 1280);
        ln_bf16<<<16384, 256, 0, stream>>>(hbuf, ln2_w + l * 1280, ln2_b + l * 1280, xn);
        gemm2ph<256, 256, 4, true, true><<<dim3(14 * 64), 512, 0, stream>>>(
            xn, fc1_wT + (size_t)l * 3584 * 1280, fc1_bp + l * 3584, ffn1,
            16384, 3584, 1280, 1280, 1280);
        gemm_db<true, true, false><<<dim3(128 * 10), 256, 0, stream>>>(
            ffn1, fc2_wT + (size_t)l * 1280 * 3456, fc2_b + l * 1280, hbuf, hbuf,
            16384, 1280, 3456, 3584, 3456);
    }

    // --- merger ---
    ln_bf16<<<16384, 256, 0, stream>>>(hbuf, mln_w, mln_b, xn);
    gemm2ph<256, 256, 4, true, true><<<dim3(20 * 16), 512, 0, stream>>>(
        xn, mfc1_wT, mfc1_b, t1, 4096, 5120, 5120, 5120, 5120);
    gemm_db<false, false, false><<<dim3(32 * 16), 256, 0, stream>>>(
        t1, mfc2_wT, mfc2_b, nullptr, (float*)d_out, 4096, 2048, 5120, 5120, 5120);
}

// Round 19
// 6717.341 us; speedup vs baseline: 1.0634x; 1.0634x over previous
//
#include <hip/hip_runtime.h>

typedef unsigned short ushortT;
typedef __attribute__((ext_vector_type(8))) short short8;
typedef __attribute__((ext_vector_type(8))) unsigned short ushort8;
typedef __attribute__((ext_vector_type(4))) unsigned short ushort4v;
typedef __attribute__((ext_vector_type(4))) float f32x4;

#define DEVINL __device__ __forceinline__

DEVINL ushortT f2bf(float f) {
    unsigned u = __builtin_bit_cast(unsigned, f);
    u += 0x7FFFu + ((u >> 16) & 1u);   // round-to-nearest-even
    return (ushortT)(u >> 16);
}
DEVINL float bf2f(ushortT h) {
    unsigned u = ((unsigned)h) << 16;
    return __builtin_bit_cast(float, u);
}
DEVINL float gelu_tanh(float x) {
    float x3 = x * x * x;
    return 0.5f * x * (1.0f + tanhf(0.7978845608028654f * (x + 0.044715f * x3)));
}

#define GLOAD_LDS16(g, l)                                                     \
    __builtin_amdgcn_global_load_lds(                                         \
        (const __attribute__((address_space(1))) void*)(g),                   \
        (__attribute__((address_space(3))) void*)(l), 16, 0, 0)

#define WAITV(n) asm volatile("s_waitcnt vmcnt(" #n ")" ::: "memory")
#define MEMFENCE() asm volatile("" ::: "memory")
#define BAR() __builtin_amdgcn_s_barrier()
#define BARF() MEMFENCE(); BAR(); MEMFENCE()

// ---------------------------------------------------------------------------
__global__ __launch_bounds__(256) void cast_bf16_4(const float* __restrict__ in,
                                                   ushortT* __restrict__ out, long n4) {
    long i = (long)blockIdx.x * 256 + threadIdx.x;
    if (i < n4) {
        const float* p = in + i * 4;
        ushort4v o;
        o[0] = f2bf(p[0]); o[1] = f2bf(p[1]); o[2] = f2bf(p[2]); o[3] = f2bf(p[3]);
        ((ushort4v*)out)[i] = o;
    }
}

// ---------------------------------------------------------------------------
__global__ __launch_bounds__(256) void transpose_cast(const float* __restrict__ in,
                                                      ushortT* __restrict__ out,
                                                      int K, int N, int Npad) {
    __shared__ float tile[32][33];
    long zi = (long)blockIdx.z * K * N;
    long zo = (long)blockIdx.z * Npad * K;
    const float* ip = in + zi;
    ushortT* op = out + zo;
    int t = threadIdx.x, bx = blockIdx.x, by = blockIdx.y;
#pragma unroll
    for (int i = 0; i < 4; i++) {
        int idx = i * 256 + t, r = idx >> 5, c = idx & 31;
        int col = bx * 32 + c;
        tile[r][c] = (col < N) ? ip[(long)(by * 32 + r) * N + col] : 0.0f;
    }
    __syncthreads();
#pragma unroll
    for (int i = 0; i < 4; i++) {
        int idx = i * 256 + t, r = idx >> 5, c = idx & 31;
        op[(long)(bx * 32 + r) * K + by * 32 + c] = f2bf(tile[c][r]);
    }
}

// pad a per-layer bias vector from n_in to n_out with zeros. total = L*n_out.
__global__ __launch_bounds__(256) void pad_bias(const float* __restrict__ in,
                                                float* __restrict__ out,
                                                int n_in, int n_out, int total) {
    int i = blockIdx.x * 256 + threadIdx.x;
    if (i < total) {
        int l = i / n_out, c = i % n_out;
        out[i] = (c < n_in) ? in[l * n_in + c] : 0.0f;
    }
}

// ---------------------------------------------------------------------------
// LayerNorm over HID=1280, bf16 in -> bf16 out. One block (256 thr) per row.
__global__ __launch_bounds__(256) void ln_bf16(const ushortT* __restrict__ in,
                                               const float* __restrict__ w,
                                               const float* __restrict__ b,
                                               ushortT* __restrict__ out) {
    const int row = blockIdx.x;
    const ushortT* x = in + (long)row * 1280;
    __shared__ float red[4];
    const int t = threadIdx.x;
    float v[8];
    float s = 0.f;
    if (t < 160) {
        ushort8 u = *(const ushort8*)(x + t * 8);
#pragma unroll
        for (int i = 0; i < 8; i++) { v[i] = bf2f(u[i]); s += v[i]; }
    } else {
#pragma unroll
        for (int i = 0; i < 8; i++) v[i] = 0.f;
    }
#pragma unroll
    for (int o = 32; o > 0; o >>= 1) s += __shfl_xor(s, o);
    int wave = t >> 6;
    if ((t & 63) == 0) red[wave] = s;
    __syncthreads();
    float mean = (red[0] + red[1] + red[2] + red[3]) * (1.0f / 1280.0f);
    float q = 0.f;
    if (t < 160) {
#pragma unroll
        for (int i = 0; i < 8; i++) { float d = v[i] - mean; q += d * d; }
    }
#pragma unroll
    for (int o = 32; o > 0; o >>= 1) q += __shfl_xor(q, o);
    __syncthreads();
    if ((t & 63) == 0) red[wave] = q;
    __syncthreads();
    float var = (red[0] + red[1] + red[2] + red[3]) * (1.0f / 1280.0f);
    float rs = rsqrtf(var + 1e-6f);
    if (t < 160) {
        ushort8 o8;
#pragma unroll
        for (int i = 0; i < 8; i++) {
            int c = t * 8 + i;
            o8[i] = f2bf((v[i] - mean) * rs * w[c] + b[c]);
        }
        *(ushort8*)(out + (long)row * 1280 + t * 8) = o8;
    }
}

// ---------------------------------------------------------------------------
// Kernel A (r15-verified): 128x128, 4 waves, BK=32, double-buffered 32KB LDS,
// __launch_bounds__(256,2). Used for: pe, proj, fc2, merger-fc2
// (N=1280-class: grid 1280 = 5 blocks/CU, no tail; measured 347 us on fc2).
#define GSTAGE(mat, ls, base, ld, k0, buf)                                    \
    _Pragma("unroll") for (int j = 0; j < 2; j++) {                           \
        int c = j * 256 + t; int sr = c >> 2, sl = c & 3;                     \
        GLOAD_LDS16(mat + (base + sr) * (size_t)ld + (k0) + ((sl ^ ((sr >> 1) & 3)) * 8), \
                    &ls[buf][c * 8]);                                         \
    }
#define GREAD(buf)                                                            \
    _Pragma("unroll") for (int m = 0; m < 4; m++) {                           \
        int r = wr * 64 + m * 16 + lr;                                        \
        aF[m] = *(const short8*)&lsA[buf][r * 32 + ((lg ^ ((r >> 1) & 3)) * 8)]; \
    }                                                                         \
    _Pragma("unroll") for (int n = 0; n < 4; n++) {                           \
        int r = wc * 64 + n * 16 + lr;                                        \
        bF[n] = *(const short8*)&lsB[buf][r * 32 + ((lg ^ ((r >> 1) & 3)) * 8)]; \
    }
#define GMFMA()                                                               \
    __builtin_amdgcn_s_setprio(1);                                            \
    _Pragma("unroll") for (int m = 0; m < 4; m++)                             \
    _Pragma("unroll") for (int n = 0; n < 4; n++)                             \
        acc[m][n] = __builtin_amdgcn_mfma_f32_16x16x32_bf16(                  \
            aF[m], bF[n], acc[m][n], 0, 0, 0);                                \
    __builtin_amdgcn_s_setprio(0);

template <bool OBF, bool RESB, bool GEL>
__global__ __launch_bounds__(256, 2)
void gemm_db(const ushortT* __restrict__ A, const ushortT* __restrict__ Bt,
             const float* __restrict__ bias, const ushortT* __restrict__ resb,
             void* __restrict__ out, int M, int N, int K, int lda, int ldb) {
    __shared__ ushortT lsA[2][4096];
    __shared__ ushortT lsB[2][4096];
    const int t = threadIdx.x;
    const int lane = t & 63, lr = lane & 15, lg = lane >> 4;
    const int wave = t >> 6;
    const int wr = wave >> 1, wc = wave & 1;

    const int nwg = gridDim.x, orig = blockIdx.x;
    const int q = nwg >> 3, r8 = nwg & 7;
    const int xcd = orig & 7, loc = orig >> 3;
    const int wg = (xcd < r8 ? xcd * (q + 1) : r8 * (q + 1) + (xcd - r8) * q) + loc;
    const int gx = N >> 7;
    const size_t brow = (size_t)(wg / gx) * 128;
    const size_t bcol = (size_t)(wg % gx) * 128;

    f32x4 acc[4][4];
#pragma unroll
    for (int m = 0; m < 4; m++)
#pragma unroll
        for (int n = 0; n < 4; n++) acc[m][n] = f32x4{0.f, 0.f, 0.f, 0.f};

    GSTAGE(A, lsA, brow, lda, 0, 0);
    GSTAGE(Bt, lsB, bcol, ldb, 0, 0);
    WAITV(0); BARF();

    short8 aF[4], bF[4];
    const int NT = K >> 5;
    int cur = 0;
    for (int tt = 0; tt < NT; ++tt) {
        MEMFENCE();
        GREAD(cur);
        if (tt + 1 < NT) {
            const int k1 = (tt + 1) << 5;
            GSTAGE(A, lsA, brow, lda, k1, cur ^ 1);
            GSTAGE(Bt, lsB, bcol, ldb, k1, cur ^ 1);
        }
        GMFMA();
        if (tt + 1 < NT) {
            WAITV(0);
            BARF();
        }
        cur ^= 1;
    }

#pragma unroll
    for (int m = 0; m < 4; m++) {
#pragma unroll
        for (int n = 0; n < 4; n++) {
#pragma unroll
            for (int rr = 0; rr < 4; rr++) {
                size_t row = brow + wr * 64 + m * 16 + lg * 4 + rr;
                size_t col = bcol + wc * 64 + n * 16 + lr;
                float v = acc[m][n][rr] + bias[col];
                if (RESB) v += bf2f(resb[row * N + col]);
                if (GEL) v = gelu_tanh(v);
                if (OBF) ((ushortT*)out)[row * N + col] = f2bf(v);
                else     ((float*)out)[row * N + col] = v;
            }
        }
    }
}

// ---------------------------------------------------------------------------
// Kernel B (r16-verified): BM=256 x BN=128, 4 waves (2M x 2N), 128x64 per
// wave, BK=32, double-buffered 48KB LDS, __launch_bounds__(256,2). Best on
// K=1280 wide-N GEMMs (halves A-fetch: 318 MB). Used for: qkv, fc1,
// merger-fc1.
#define WSTAGE_A(k0, buf)                                                     \
    _Pragma("unroll") for (int j = 0; j < 4; j++) {                           \
        int c = j * 256 + t; int sr = c >> 2, sl = c & 3;                     \
        GLOAD_LDS16(A + (brow + sr) * (size_t)lda + (k0) + ((sl ^ ((sr >> 1) & 3)) * 8), \
                    &lsA[buf][c * 8]);                                        \
    }
#define WSTAGE_B(k0, buf)                                                     \
    _Pragma("unroll") for (int j = 0; j < 2; j++) {                           \
        int c = j * 256 + t; int sr = c >> 2, sl = c & 3;                     \
        GLOAD_LDS16(Bt + (bcol + sr) * (size_t)ldb + (k0) + ((sl ^ ((sr >> 1) & 3)) * 8), \
                    &lsB[buf][c * 8]);                                        \
    }
#define WREAD(buf)                                                            \
    _Pragma("unroll") for (int m = 0; m < 8; m++) {                           \
        int r = wr * 128 + m * 16 + lr;                                       \
        aF[m] = *(const short8*)&lsA[buf][r * 32 + ((lg ^ ((r >> 1) & 3)) * 8)]; \
    }                                                                         \
    _Pragma("unroll") for (int n = 0; n < 4; n++) {                           \
        int r = wc * 64 + n * 16 + lr;                                        \
        bF[n] = *(const short8*)&lsB[buf][r * 32 + ((lg ^ ((r >> 1) & 3)) * 8)]; \
    }
#define WMFMA()                                                               \
    __builtin_amdgcn_s_setprio(1);                                            \
    _Pragma("unroll") for (int m = 0; m < 8; m++)                             \
    _Pragma("unroll") for (int n = 0; n < 4; n++)                             \
        acc[m][n] = __builtin_amdgcn_mfma_f32_16x16x32_bf16(                  \
            aF[m], bF[n], acc[m][n], 0, 0, 0);                                \
    __builtin_amdgcn_s_setprio(0);

template <bool OBF, bool RESB, bool GEL>
__global__ __launch_bounds__(256, 2)
void gemm_wide(const ushortT* __restrict__ A, const ushortT* __restrict__ Bt,
               const float* __restrict__ bias, const ushortT* __restrict__ resb,
               void* __restrict__ out, int M, int N, int K, int lda, int ldb) {
    __shared__ ushortT lsA[2][8192];   // 256 x 32 bf16
    __shared__ ushortT lsB[2][4096];   // 128 x 32 bf16
    const int t = threadIdx.x;
    const int lane = t & 63, lr = lane & 15, lg = lane >> 4;
    const int wave = t >> 6;
    const int wr = wave >> 1, wc = wave & 1;

    const int nwg = gridDim.x, orig = blockIdx.x;
    const int q = nwg >> 3, r8 = nwg & 7;
    const int xcd = orig & 7, loc = orig >> 3;
    const int wg = (xcd < r8 ? xcd * (q + 1) : r8 * (q + 1) + (xcd - r8) * q) + loc;
    const int gx = N >> 7;
    const size_t brow = (size_t)(wg / gx) * 256;
    const size_t bcol = (size_t)(wg % gx) * 128;

    f32x4 acc[8][4];
#pragma unroll
    for (int m = 0; m < 8; m++)
#pragma unroll
        for (int n = 0; n < 4; n++) acc[m][n] = f32x4{0.f, 0.f, 0.f, 0.f};

    WSTAGE_A(0, 0);
    WSTAGE_B(0, 0);
    WAITV(0); BARF();

    short8 aF[8], bF[4];
    const int NT = K >> 5;
    int cur = 0;
    for (int tt = 0; tt < NT; ++tt) {
        MEMFENCE();
        WREAD(cur);
        if (tt + 1 < NT) {
            const int k1 = (tt + 1) << 5;
            WSTAGE_A(k1, cur ^ 1);
            WSTAGE_B(k1, cur ^ 1);
        }
        WMFMA();
        if (tt + 1 < NT) {
            WAITV(0);
            BARF();
        }
        cur ^= 1;
    }

#pragma unroll
    for (int m = 0; m < 8; m++) {
#pragma unroll
        for (int n = 0; n < 4; n++) {
#pragma unroll
            for (int rr = 0; rr < 4; rr++) {
                size_t row = brow + wr * 128 + m * 16 + lg * 4 + rr;
                size_t col = bcol + wc * 64 + n * 16 + lr;
                float v = acc[m][n][rr] + bias[col];
                if (RESB) v += bf2f(resb[row * N + col]);
                if (GEL) v = gelu_tanh(v);
                if (OBF) ((ushortT*)out)[row * N + col] = f2bf(v);
                else     ((float*)out)[row * N + col] = v;
            }
        }
    }
}

// ---------------------------------------------------------------------------
// windowed attention with fused RoPE: one block per (window of 64 tokens, head).
__global__ __launch_bounds__(256) void attn_win(const ushortT* __restrict__ qkv,
                                                const float* __restrict__ cosb,
                                                const float* __restrict__ sinb,
                                                ushortT* __restrict__ out) {
    const int w = blockIdx.x, h = blockIdx.y;
    __shared__ ushortT qs[64 * 96];
    __shared__ ushortT ks[64 * 96];
    __shared__ ushortT vt[80 * 80];
    __shared__ float   sc[64 * 65];
    __shared__ ushortT pb[64 * 80];
    const int t = threadIdx.x, wave = t >> 6, lane = t & 63, lr = lane & 15, lg = lane >> 4;
    const ushortT* bq = qkv + (long)w * 64 * 3840 + h * 80;

    for (int c = t; c < 640; c += 256) {
        int r = c / 10, cb = c % 10;
        const ushortT* qp = bq + (long)r * 3840;
        ushort8 qa = *(const ushort8*)(qp + cb * 8);
        ushort8 ka = *(const ushort8*)(qp + 1280 + cb * 8);
        int pcb = (cb < 5) ? cb + 5 : cb - 5;
        ushort8 qpr = *(const ushort8*)(qp + pcb * 8);
        ushort8 kpr = *(const ushort8*)(qp + 1280 + pcb * 8);
        long srow = (long)w * 64 + r;
        const float* cp = cosb + srow * 80 + cb * 8;
        const float* sp = sinb + srow * 80 + cb * 8;
        float sgn = (cb < 5) ? -1.f : 1.f;
        ushort8 qo, ko;
#pragma unroll
        for (int j = 0; j < 8; j++) {
            float c_ = cp[j], s_ = sp[j] * sgn;
            qo[j] = f2bf(bf2f(qa[j]) * c_ + bf2f(qpr[j]) * s_);
            ko[j] = f2bf(bf2f(ka[j]) * c_ + bf2f(kpr[j]) * s_);
        }
        *(ushort8*)&qs[r * 96 + cb * 8] = qo;
        *(ushort8*)&ks[r * 96 + cb * 8] = ko;
        ushort8 vv = *(const ushort8*)(qp + 2560 + cb * 8);
#pragma unroll
        for (int j = 0; j < 8; j++) vt[(cb * 8 + j) * 80 + r] = vv[j];
    }
    for (int idx = t; idx < 1024; idx += 256) {
        int r = idx >> 4, c2 = 80 + (idx & 15);
        qs[r * 96 + c2] = 0;
        ks[r * 96 + c2] = 0;
    }
    __syncthreads();

    f32x4 sa[4];
#pragma unroll
    for (int n = 0; n < 4; n++) sa[n] = f32x4{0.f, 0.f, 0.f, 0.f};
#pragma unroll
    for (int kk = 0; kk < 3; kk++) {
        short8 aq = *(const short8*)&qs[(wave * 16 + lr) * 96 + kk * 32 + lg * 8];
#pragma unroll
        for (int n = 0; n < 4; n++) {
            short8 bk = *(const short8*)&ks[(n * 16 + lr) * 96 + kk * 32 + lg * 8];
            sa[n] = __builtin_amdgcn_mfma_f32_16x16x32_bf16(aq, bk, sa[n], 0, 0, 0);
        }
    }
    const float scale = 0.11180339887498949f;
#pragma unroll
    for (int n = 0; n < 4; n++)
#pragma unroll
        for (int r = 0; r < 4; r++)
            sc[(wave * 16 + lg * 4 + r) * 65 + n * 16 + lr] = sa[n][r] * scale;
    __syncthreads();

    {
        int row = t >> 2, q4 = t & 3;
        float pv[16];
        float mx = -1e30f;
#pragma unroll
        for (int j = 0; j < 16; j++) { pv[j] = sc[row * 65 + q4 * 16 + j]; mx = fmaxf(mx, pv[j]); }
        mx = fmaxf(mx, __shfl_xor(mx, 1));
        mx = fmaxf(mx, __shfl_xor(mx, 2));
        float sum = 0.f;
#pragma unroll
        for (int j = 0; j < 16; j++) { pv[j] = __expf(pv[j] - mx); sum += pv[j]; }
        sum += __shfl_xor(sum, 1);
        sum += __shfl_xor(sum, 2);
        float inv = 1.0f / sum;
#pragma unroll
        for (int j = 0; j < 16; j++) pb[row * 80 + q4 * 16 + j] = f2bf(pv[j] * inv);
    }
    __syncthreads();

    f32x4 pa[5];
#pragma unroll
    for (int n = 0; n < 5; n++) pa[n] = f32x4{0.f, 0.f, 0.f, 0.f};
#pragma unroll
    for (int kk = 0; kk < 2; kk++) {
        short8 ap = *(const short8*)&pb[(wave * 16 + lr) * 80 + kk * 32 + lg * 8];
#pragma unroll
        for (int n = 0; n < 5; n++) {
            short8 bv = *(const short8*)&vt[(n * 16 + lr) * 80 + kk * 32 + lg * 8];
            pa[n] = __builtin_amdgcn_mfma_f32_16x16x32_bf16(ap, bv, pa[n], 0, 0, 0);
        }
    }
    ushortT* ob = out + (long)w * 64 * 1280 + h * 80;
#pragma unroll
    for (int n = 0; n < 5; n++)
#pragma unroll
        for (int r = 0; r < 4; r++)
            ob[(long)(wave * 16 + lg * 4 + r) * 1280 + n * 16 + lr] = f2bf(pa[n][r]);
}

// ---------------------------------------------------------------------------
extern "C" void kernel_launch(void* const* d_in, const int* in_sizes, int n_in,
                              void* d_out, int out_size, void* d_ws, size_t ws_size,
                              hipStream_t stream) {
    const float* x      = (const float*)d_in[0];
    const float* cosb   = (const float*)d_in[1];
    const float* sinb   = (const float*)d_in[2];
    const float* pe_w   = (const float*)d_in[4];
    const float* pe_b   = (const float*)d_in[5];
    const float* ln1_w  = (const float*)d_in[6];
    const float* ln1_b  = (const float*)d_in[7];
    const float* qkv_w  = (const float*)d_in[8];
    const float* qkv_b  = (const float*)d_in[9];
    const float* proj_w = (const float*)d_in[10];
    const float* proj_b = (const float*)d_in[11];
    const float* ln2_w  = (const float*)d_in[12];
    const float* ln2_b  = (const float*)d_in[13];
    const float* fc1_w  = (const float*)d_in[14];
    const float* fc1_b  = (const float*)d_in[15];
    const float* fc2_w  = (const float*)d_in[16];
    const float* fc2_b  = (const float*)d_in[17];
    const float* mln_w  = (const float*)d_in[18];
    const float* mln_b  = (const float*)d_in[19];
    const float* mfc1_w = (const float*)d_in[20];
    const float* mfc1_b = (const float*)d_in[21];
    const float* mfc2_w = (const float*)d_in[22];
    const float* mfc2_b = (const float*)d_in[23];

    char* ws = (char*)d_ws;
    size_t off = 0;
    auto alloc = [&](size_t bytes) -> char* {
        char* p = ws + off;
        off += (bytes + 255) & ~(size_t)255;
        return p;
    };
    ushortT* pe_wT   = (ushortT*)alloc((size_t)1280 * 1536 * 2);
    ushortT* qkv_wT  = (ushortT*)alloc((size_t)8 * 3840 * 1280 * 2);
    ushortT* proj_wT = (ushortT*)alloc((size_t)8 * 1280 * 1280 * 2);
    ushortT* fc1_wT  = (ushortT*)alloc((size_t)8 * 3584 * 1280 * 2);  // N padded 3456->3584
    ushortT* fc2_wT  = (ushortT*)alloc((size_t)8 * 1280 * 3456 * 2);
    ushortT* mfc1_wT = (ushortT*)alloc((size_t)5120 * 5120 * 2);
    ushortT* mfc2_wT = (ushortT*)alloc((size_t)2048 * 5120 * 2);
    float*   fc1_bp  = (float*)alloc((size_t)8 * 3584 * 4);
    ushortT* hbuf    = (ushortT*)alloc((size_t)16384 * 1280 * 2);     // residual, bf16
    ushortT* xn      = (ushortT*)alloc((size_t)16384 * 1280 * 2);
    ushortT* big     = (ushortT*)alloc((size_t)16384 * 3840 * 2);     // qkv / x_bf16 / ffn1
    ushortT* attnb   = (ushortT*)alloc((size_t)16384 * 1280 * 2);     // also merger t1

    ushortT* xbf  = big;
    ushortT* qkvb = big;
    ushortT* ffn1 = big;
    ushortT* t1   = attnb;

    transpose_cast<<<dim3(1280 / 32, 1536 / 32, 1), 256, 0, stream>>>(pe_w,   pe_wT,   1536, 1280, 1280);
    transpose_cast<<<dim3(3840 / 32, 1280 / 32, 8), 256, 0, stream>>>(qkv_w,  qkv_wT,  1280, 3840, 3840);
    transpose_cast<<<dim3(1280 / 32, 1280 / 32, 8), 256, 0, stream>>>(proj_w, proj_wT, 1280, 1280, 1280);
    transpose_cast<<<dim3(3584 / 32, 1280 / 32, 8), 256, 0, stream>>>(fc1_w,  fc1_wT,  1280, 3456, 3584);
    transpose_cast<<<dim3(1280 / 32, 3456 / 32, 8), 256, 0, stream>>>(fc2_w,  fc2_wT,  3456, 1280, 1280);
    transpose_cast<<<dim3(5120 / 32, 5120 / 32, 1), 256, 0, stream>>>(mfc1_w, mfc1_wT, 5120, 5120, 5120);
    transpose_cast<<<dim3(2048 / 32, 5120 / 32, 1), 256, 0, stream>>>(mfc2_w, mfc2_wT, 5120, 2048, 2048);
    pad_bias<<<(8 * 3584 + 255) / 256, 256, 0, stream>>>(fc1_b, fc1_bp, 3456, 3584, 8 * 3584);

    // --- patch embed: h = x @ pe_w + pe_b (h bf16) ---
    cast_bf16_4<<<(16384L * 1536 / 4 + 255) / 256, 256, 0, stream>>>(x, xbf, 16384L * 1536 / 4);
    gemm_db<true, false, false><<<dim3(128 * 10), 256, 0, stream>>>(
        xbf, pe_wT, pe_b, nullptr, hbuf, 16384, 1280, 1536, 1536, 1536);

    // --- transformer layers ---
    for (int l = 0; l < 8; l++) {
        ln_bf16<<<16384, 256, 0, stream>>>(hbuf, ln1_w + l * 1280, ln1_b + l * 1280, xn);
        gemm_wide<true, false, false><<<dim3(64 * 30), 256, 0, stream>>>(
            xn, qkv_wT + (size_t)l * 3840 * 1280, qkv_b + l * 3840, nullptr, qkvb,
            16384, 3840, 1280, 1280, 1280);
        attn_win<<<dim3(256, 16), 256, 0, stream>>>(qkvb, cosb, sinb, attnb);
        gemm_db<true, true, false><<<dim3(128 * 10), 256, 0, stream>>>(
            attnb, proj_wT + (size_t)l * 1280 * 1280, proj_b + l * 1280, hbuf, hbuf,
            16384, 1280, 1280, 1280, 1280);
        ln_bf16<<<16384, 256, 0, stream>>>(hbuf, ln2_w + l * 1280, ln2_b + l * 1280, xn);
        gemm_wide<true, false, true><<<dim3(64 * 28), 256, 0, stream>>>(
            xn, fc1_wT + (size_t)l * 3584 * 1280, fc1_bp + l * 3584, nullptr, ffn1,
            16384, 3584, 1280, 1280, 1280);
        gemm_db<true, true, false><<<dim3(128 * 10), 256, 0, stream>>>(
            ffn1, fc2_wT + (size_t)l * 1280 * 3456, fc2_b + l * 1280, hbuf, hbuf,
            16384, 1280, 3456, 3584, 3456);
    }

    // --- merger ---
    ln_bf16<<<16384, 256, 0, stream>>>(hbuf, mln_w, mln_b, xn);
    gemm_wide<true, false, true><<<dim3(16 * 40), 256, 0, stream>>>(
        xn, mfc1_wT, mfc1_b, nullptr, t1, 4096, 5120, 5120, 5120, 5120);
    gemm_db<false, false, false><<<dim3(32 * 16), 256, 0, stream>>>(
        t1, mfc2_wT, mfc2_b, nullptr, (float*)d_out, 4096, 2048, 5120, 5120, 5120);
}